// Round 1
// baseline (328.442 us; speedup 1.0000x reference)
//
#include <hip/hip_runtime.h>
#include <hip/hip_bf16.h>

#define DEV __device__ __forceinline__

typedef __attribute__((ext_vector_type(8))) short bhalf8;   // 8 bf16 (4 VGPR)
typedef __attribute__((ext_vector_type(4))) float f32x4;    // MFMA C/D
typedef __attribute__((ext_vector_type(4))) float f4v;

// ---- workspace layout (bytes) ----
constexpr size_t OFF_WE1HI = 0;         // [128][512] bf16
constexpr size_t OFF_WE1LO = 131072;
constexpr size_t OFF_WE2HI = 262144;
constexpr size_t OFF_WE2LO = 393216;
constexpr size_t OFF_WCA   = 524288;    // [32][256] bf16
constexpr size_t OFF_WCV   = 540672;
constexpr size_t OFF_WR1HI = 557056;    // [128][256] bf16
constexpr size_t OFF_WR1LO = 622592;
constexpr size_t OFF_AUD   = 688128;    // [32768][128] f32
constexpr size_t OFF_VIS   = 17465344;  // [32768][128] f32  (total ~32.7 MB)

DEV short f2bf(float f) {               // RNE float->bf16 bits
    __hip_bfloat16 h = __float2bfloat16(f);
    return __builtin_bit_cast(short, h);
}
DEV float bf2f(short s) {
    unsigned u = ((unsigned)(unsigned short)s) << 16;
    return __builtin_bit_cast(float, u);
}
DEV float fexp2(float x) { float r; asm("v_exp_f32 %0, %1" : "=v"(r) : "v"(x)); return r; }
DEV float frcp (float x) { float r; asm("v_rcp_f32 %0, %1" : "=v"(r) : "v"(x)); return r; }

// wave-local LDS write->read (and read->write) ordering
#define WFENCE() asm volatile("s_waitcnt lgkmcnt(0)" ::: "memory")
#define MFMA(a,b,c) __builtin_amdgcn_mfma_f32_16x16x32_bf16(a,b,c,0,0,0)

// ---------------- prep: bf16 (hi/lo) conversion of big weights ----------------
__global__ void k_prep(const float* __restrict__ We1, const float* __restrict__ We2,
                       const float* __restrict__ Wca, const float* __restrict__ Wcv,
                       const float* __restrict__ Wr1, char* __restrict__ ws)
{
    int idx = blockIdx.x * 256 + threadIdx.x;      // 65536 threads
    short* we1hi = (short*)(ws + OFF_WE1HI);
    short* we1lo = (short*)(ws + OFF_WE1LO);
    short* we2hi = (short*)(ws + OFF_WE2HI);
    short* we2lo = (short*)(ws + OFF_WE2LO);
    short* wca   = (short*)(ws + OFF_WCA);
    short* wcv   = (short*)(ws + OFF_WCV);
    short* w1hi  = (short*)(ws + OFF_WR1HI);
    short* w1lo  = (short*)(ws + OFF_WR1LO);

    float v = We1[idx]; short h = f2bf(v);
    we1hi[idx] = h; we1lo[idx] = f2bf(v - bf2f(h));
    v = We2[idx]; h = f2bf(v);
    we2hi[idx] = h; we2lo[idx] = f2bf(v - bf2f(h));
    if (idx < 8192) { wca[idx] = f2bf(Wca[idx]); wcv[idx] = f2bf(Wcv[idx]); }
    if (idx < 32768) {
        v = Wr1[idx]; h = f2bf(v);
        w1hi[idx] = h; w1lo[idx] = f2bf(v - bf2f(h));
    }
}

// ---------------- encoder: aud/vis = f @ We^T + be  (3-pass hi/lo bf16 MFMA) --
__global__ __launch_bounds__(256) void k_encoder(
    const float* __restrict__ f1, const float* __restrict__ f2,
    const float* __restrict__ be1, const float* __restrict__ be2,
    char* __restrict__ ws)
{
    const int w  = threadIdx.x >> 6;
    const int l  = threadIdx.x & 63;
    const int lr = l & 15, lg = l >> 4;
    const long row = (long)blockIdx.x * 64 + w * 16 + lr;   // A-operand row

    for (int mod = 0; mod < 2; ++mod) {
        const float* f  = mod ? f2 : f1;
        const short* whi = (const short*)(ws + (mod ? OFF_WE2HI : OFF_WE1HI));
        const short* wlo = (const short*)(ws + (mod ? OFF_WE2LO : OFF_WE1LO));
        const float* be  = mod ? be2 : be1;
        float* outp = (float*)(ws + (mod ? OFF_VIS : OFF_AUD));

        f32x4 acc[8];
        #pragma unroll
        for (int nt = 0; nt < 8; ++nt) acc[nt] = (f32x4){0.f,0.f,0.f,0.f};

        for (int ks = 0; ks < 16; ++ks) {
            const int k0 = ks * 32 + lg * 8;
            const float* ap = f + row * 512 + k0;
            f4v a0 = *(const f4v*)ap;
            f4v a1 = *(const f4v*)(ap + 4);
            float av[8] = {a0[0],a0[1],a0[2],a0[3],a1[0],a1[1],a1[2],a1[3]};
            bhalf8 ahi, alo;
            #pragma unroll
            for (int i = 0; i < 8; ++i) {
                short h = f2bf(av[i]);
                ahi[i] = h;
                alo[i] = f2bf(av[i] - bf2f(h));
            }
            #pragma unroll
            for (int nt = 0; nt < 8; ++nt) {
                const int wrow = nt * 16 + lr;
                bhalf8 bhi = *(const bhalf8*)(whi + wrow * 512 + k0);
                bhalf8 blo = *(const bhalf8*)(wlo + wrow * 512 + k0);
                acc[nt] = MFMA(ahi, bhi, acc[nt]);
                acc[nt] = MFMA(alo, bhi, acc[nt]);
                acc[nt] = MFMA(ahi, blo, acc[nt]);
            }
        }
        const long orow = (long)blockIdx.x * 64 + w * 16 + lg * 4;
        #pragma unroll
        for (int nt = 0; nt < 8; ++nt) {
            const int col = nt * 16 + lr;
            const float bias = be[col];
            #pragma unroll
            for (int r = 0; r < 4; ++r)
                outp[(orow + r) * 128 + col] = acc[nt][r] + bias;
        }
    }
}

// ---------------- fused middle + regressor: one block per batch ---------------
__global__ __launch_bounds__(256) void k_fused(
    const float* __restrict__ waffa, const float* __restrict__ waffv,
    const float* __restrict__ Wa,   const float* __restrict__ Wv,
    const float* __restrict__ Wha,  const float* __restrict__ Whv,
    const float* __restrict__ br1,  const float* __restrict__ Wr2,
    const float* __restrict__ br2,
    const char* __restrict__ ws, float* __restrict__ out)
{
    __shared__ float s_av[2][8][128];                    // aud/vis fp32
    __shared__ __align__(16) short s_At[2][128][8];      // A^T bf16 (M-GEMM A)
    __shared__ __align__(16) short s_G[2][256][8];       // folded G bf16 (M-GEMM B)
    __shared__ __align__(16) short s_z[128 * 64];        // tanh chunk, XOR-swizzled
    __shared__ __align__(16) short s_H[128][40];         // relu(H) bf16 (pad 40)
    __shared__ __align__(16) short s_fhi[16][264];       // avf hi (pad 264)
    __shared__ __align__(16) short s_flo[16][264];       // avf lo
    __shared__ float s_h[8][128];
    __shared__ float s_waff[2][8][8];
    __shared__ float s_red[8][8];

    const int tid = threadIdx.x;
    const int b = blockIdx.x;
    const int w = tid >> 6, l = tid & 63, lr = l & 15, lg = l >> 4;
    const bool k8 = (lg == 0);          // lanes carrying the real K=8 slice

    const short* wcag  = (const short*)(ws + OFF_WCA);
    const short* wcvg  = (const short*)(ws + OFF_WCV);
    const short* wr1hi = (const short*)(ws + OFF_WR1HI);
    const short* wr1lo = (const short*)(ws + OFF_WR1LO);
    const float* audp = (const float*)(ws + OFF_AUD) + (long)b * 1024;
    const float* visp = (const float*)(ws + OFF_VIS) + (long)b * 1024;

    // phase 0: stage aud/vis (fp32 + bf16 transpose)
    #pragma unroll
    for (int i = 0; i < 4; ++i) {
        int idx = tid + 256 * i;          // 0..1023  ([t][i] layout)
        int tt = idx >> 7, ii = idx & 127;
        float va = audp[idx], vv = visp[idx];
        s_av[0][tt][ii] = va; s_At[0][ii][tt] = f2bf(va);
        s_av[1][tt][ii] = vv; s_At[1][ii][tt] = f2bf(vv);
    }
    if (tid < 128) {
        const float* src = (tid < 64) ? waffa : waffv;
        s_waff[tid >> 6][(tid >> 3) & 7][tid & 7] = src[tid & 63];
    }
    __syncthreads();

    // phase 1: G' = (Waff @ av) * (scale*2*log2e)   [tanh prefold]
    const float kfold = (1.0f / 16.0f) * 2.0f * 1.44269504088896340736f;
    #pragma unroll
    for (int u = 0; u < 2; ++u) {
        int idx = tid + 256 * u;           // 0..511
        int m = idx >> 8, j = idx & 255;
        float g[8] = {0,0,0,0,0,0,0,0};
        #pragma unroll
        for (int t = 0; t < 8; ++t) {
            float av = (j < 128) ? s_av[0][t][j] : s_av[1][t][j - 128];
            #pragma unroll
            for (int p = 0; p < 8; ++p) g[p] += s_waff[m][p][t] * av;
        }
        #pragma unroll
        for (int p = 0; p < 8; ++p) s_G[m][j][p] = f2bf(g[p] * kfold);
    }
    __syncthreads();

    const bhalf8 zf8 = {0,0,0,0,0,0,0,0};
    const f32x4  zf4 = {0.f,0.f,0.f,0.f};

    // phase 2: per modality — M=tanh(At@G'), H=relu(M@Wca^T + At@Wa^T), out_a=H@Wha^T
    for (int mod = 0; mod < 2; ++mod) {
        const short* wca = mod ? wcvg : wcag;
        const float* wha = mod ? Whv : Wha;
        const float* wa  = mod ? Wv  : Wa;

        bhalf8 atf[2];
        #pragma unroll
        for (int mt = 0; mt < 2; ++mt)
            atf[mt] = k8 ? *(const bhalf8*)&s_At[mod][(2*w+mt)*16 + lr][0] : zf8;

        f32x4 hacc[2][2];
        #pragma unroll
        for (int nt = 0; nt < 2; ++nt) {        // H init: At @ Wa^T  (K=8)
            bhalf8 wf = zf8;
            if (k8) {
                const float* p = wa + (nt*16 + lr) * 8;
                #pragma unroll
                for (int i = 0; i < 8; ++i) wf[i] = f2bf(p[i]);
            }
            #pragma unroll
            for (int mt = 0; mt < 2; ++mt) hacc[mt][nt] = MFMA(atf[mt], wf, zf4);
        }

        for (int cc = 0; cc < 4; ++cc) {        // 4 chunks of 64 cols
            f32x4 macc[2][4];
            #pragma unroll
            for (int nt = 0; nt < 4; ++nt) {
                bhalf8 gf = k8 ? *(const bhalf8*)&s_G[mod][cc*64 + nt*16 + lr][0] : zf8;
                #pragma unroll
                for (int mt = 0; mt < 2; ++mt) macc[mt][nt] = MFMA(atf[mt], gf, zf4);
            }
            WFENCE();   // prior chunk's z reads complete before overwrite
            #pragma unroll
            for (int mt = 0; mt < 2; ++mt)
            #pragma unroll
            for (int nt = 0; nt < 4; ++nt)
            #pragma unroll
            for (int r = 0; r < 4; ++r) {
                int zr = (2*w+mt)*16 + lg*4 + r;
                int zc = nt*16 + lr;
                float e  = fexp2(macc[mt][nt][r]);           // exp2 prefolded
                float zv = fmaf(-2.0f, frcp(e + 1.0f), 1.0f); // tanh
                int off = (zr * 128 + zc * 2) ^ ((zr & 7) << 4);
                *(short*)((char*)s_z + off) = f2bf(zv);
            }
            WFENCE();   // writes visible before reads
            #pragma unroll
            for (int ks = 0; ks < 2; ++ks) {
                bhalf8 az[2];
                #pragma unroll
                for (int mt = 0; mt < 2; ++mt) {
                    int mrow = (2*w+mt)*16 + lr;
                    int off = (mrow * 128 + (ks*32 + lg*8) * 2) ^ ((mrow & 7) << 4);
                    az[mt] = *(const bhalf8*)((const char*)s_z + off);
                }
                #pragma unroll
                for (int nt = 0; nt < 2; ++nt) {
                    bhalf8 bw = *(const bhalf8*)(wca + (nt*16 + lr)*256 + cc*64 + ks*32 + lg*8);
                    #pragma unroll
                    for (int mt = 0; mt < 2; ++mt)
                        hacc[mt][nt] = MFMA(az[mt], bw, hacc[mt][nt]);
                }
            }
        }
        WFENCE();
        #pragma unroll
        for (int mt = 0; mt < 2; ++mt)          // relu -> s_H
        #pragma unroll
        for (int nt = 0; nt < 2; ++nt)
        #pragma unroll
        for (int r = 0; r < 4; ++r) {
            int hr = (2*w+mt)*16 + lg*4 + r;
            s_H[hr][nt*16 + lr] = f2bf(fmaxf(hacc[mt][nt][r], 0.0f));
        }
        WFENCE();
        bhalf8 whaf = zf8;                       // Wha^T B-frag (N pad to 16)
        if (lr < 8) {
            const float* p = wha + lr*32 + lg*8;
            #pragma unroll
            for (int i = 0; i < 8; ++i) whaf[i] = f2bf(p[i]);
        }
        #pragma unroll
        for (int mt = 0; mt < 2; ++mt) {
            int hrow = (2*w+mt)*16 + lr;
            bhalf8 af = *(const bhalf8*)&s_H[hrow][lg*8];
            f32x4 oa = MFMA(af, whaf, zf4);
            if (lr < 8) {
                #pragma unroll
                for (int r = 0; r < 4; ++r) {
                    int irow = (2*w+mt)*16 + lg*4 + r;
                    float val = oa[r] + s_av[mod][lr][irow];   // residual fp32
                    short hi = f2bf(val);
                    s_fhi[lr][mod*128 + irow] = hi;
                    s_flo[lr][mod*128 + irow] = f2bf(val - bf2f(hi));
                }
            }
        }
        WFENCE();   // s_H reads done before next modality overwrites
    }
    __syncthreads();

    // phase 3: h = avf @ Wr1^T + br1   (hi/lo split: 3 passes)
    f32x4 hago[2] = {zf4, zf4};
    #pragma unroll
    for (int ks = 0; ks < 8; ++ks) {
        bhalf8 ahi = *(const bhalf8*)&s_fhi[lr][ks*32 + lg*8];
        bhalf8 alo = *(const bhalf8*)&s_flo[lr][ks*32 + lg*8];
        #pragma unroll
        for (int nt = 0; nt < 2; ++nt) {
            int n = w*32 + nt*16 + lr;
            bhalf8 bhi = *(const bhalf8*)(wr1hi + n*256 + ks*32 + lg*8);
            bhalf8 blo = *(const bhalf8*)(wr1lo + n*256 + ks*32 + lg*8);
            hago[nt] = MFMA(ahi, bhi, hago[nt]);
            hago[nt] = MFMA(alo, bhi, hago[nt]);
            hago[nt] = MFMA(ahi, blo, hago[nt]);
        }
    }
    #pragma unroll
    for (int nt = 0; nt < 2; ++nt)
    #pragma unroll
    for (int r = 0; r < 4; ++r) {
        int trow = lg*4 + r;
        if (trow < 8) {
            int n = w*32 + nt*16 + lr;
            s_h[trow][n] = hago[nt][r] + br1[n];
        }
    }
    __syncthreads();

    // phase 4: out = h @ Wr2^T + br2
    if (tid < 64) {
        int t = tid >> 3, seg = tid & 7;
        float s = 0.0f;
        #pragma unroll
        for (int q = 0; q < 16; ++q)
            s += s_h[t][seg*16 + q] * Wr2[seg*16 + q];
        s_red[t][seg] = s;
    }
    __syncthreads();
    if (tid < 8) {
        float s = br2[0];
        #pragma unroll
        for (int q = 0; q < 8; ++q) s += s_red[tid][q];
        out[b*8 + tid] = s;
    }
}

extern "C" void kernel_launch(void* const* d_in, const int* in_sizes, int n_in,
                              void* d_out, int out_size, void* d_ws, size_t ws_size,
                              hipStream_t stream)
{
    const float* f1    = (const float*)d_in[0];
    const float* f2    = (const float*)d_in[1];
    const float* We1   = (const float*)d_in[2];
    const float* be1   = (const float*)d_in[3];
    const float* We2   = (const float*)d_in[4];
    const float* be2   = (const float*)d_in[5];
    const float* Waffa = (const float*)d_in[6];
    const float* Waffv = (const float*)d_in[7];
    const float* Wa    = (const float*)d_in[8];
    const float* Wv    = (const float*)d_in[9];
    const float* Wca   = (const float*)d_in[10];
    const float* Wcv   = (const float*)d_in[11];
    const float* Wha   = (const float*)d_in[12];
    const float* Whv   = (const float*)d_in[13];
    const float* Wr1   = (const float*)d_in[14];
    const float* br1   = (const float*)d_in[15];
    const float* Wr2   = (const float*)d_in[16];
    const float* br2   = (const float*)d_in[17];
    char* ws = (char*)d_ws;
    float* out = (float*)d_out;

    k_prep   <<<256,  256, 0, stream>>>(We1, We2, Wca, Wcv, Wr1, ws);
    k_encoder<<<512,  256, 0, stream>>>(f1, f2, be1, be2, ws);
    k_fused  <<<4096, 256, 0, stream>>>(Waffa, Waffv, Wa, Wv, Wha, Whv,
                                        br1, Wr2, br2, ws, out);
}

// Round 2
// 198.754 us; speedup vs baseline: 1.6525x; 1.6525x over previous
//
#include <hip/hip_runtime.h>
#include <hip/hip_bf16.h>

#define DEV __device__ __forceinline__

typedef __attribute__((ext_vector_type(8))) short bhalf8;   // 8 bf16 (4 VGPR)
typedef __attribute__((ext_vector_type(4))) float f32x4;    // MFMA C/D
typedef __attribute__((ext_vector_type(4))) float f4v;

// ---- workspace layout (bytes) ----
constexpr size_t OFF_WE1HI = 0;         // [128][512] bf16
constexpr size_t OFF_WE2HI = 131072;
constexpr size_t OFF_WCA   = 262144;    // [32][256] bf16
constexpr size_t OFF_WCV   = 278528;
constexpr size_t OFF_WCOMB = 294912;    // [256] f32 = W_r2 @ W_r1
constexpr size_t OFF_BC    = 295936;    // scalar f32 = b_r1.W_r2 + b_r2
constexpr size_t OFF_AUD   = 327680;    // [32768][128] f32
constexpr size_t OFF_VIS   = 17104896;  // [32768][128] f32  (total ~32.3 MB)

DEV short f2bf(float f) {               // RNE float->bf16 bits
    __hip_bfloat16 h = __float2bfloat16(f);
    return __builtin_bit_cast(short, h);
}
DEV float bf2f(short s) {
    unsigned u = ((unsigned)(unsigned short)s) << 16;
    return __builtin_bit_cast(float, u);
}
DEV float fexp2(float x) { float r; asm("v_exp_f32 %0, %1" : "=v"(r) : "v"(x)); return r; }
DEV float frcp (float x) { float r; asm("v_rcp_f32 %0, %1" : "=v"(r) : "v"(x)); return r; }

// wave-local LDS write->read (and read->write) ordering
#define WFENCE() asm volatile("s_waitcnt lgkmcnt(0)" ::: "memory")
#define MFMA(a,b,c) __builtin_amdgcn_mfma_f32_16x16x32_bf16(a,b,c,0,0,0)

// ---------------- prep: bf16 weights + collapsed regressor ----------------
__global__ void k_prep(const float* __restrict__ We1, const float* __restrict__ We2,
                       const float* __restrict__ Wca, const float* __restrict__ Wcv,
                       const float* __restrict__ Wr1, const float* __restrict__ br1,
                       const float* __restrict__ Wr2, const float* __restrict__ br2,
                       char* __restrict__ ws)
{
    int idx = blockIdx.x * 256 + threadIdx.x;      // 65536 threads
    short* we1hi = (short*)(ws + OFF_WE1HI);
    short* we2hi = (short*)(ws + OFF_WE2HI);
    short* wca   = (short*)(ws + OFF_WCA);
    short* wcv   = (short*)(ws + OFF_WCV);
    float* wcomb = (float*)(ws + OFF_WCOMB);
    float* bcp   = (float*)(ws + OFF_BC);

    we1hi[idx] = f2bf(We1[idx]);
    we2hi[idx] = f2bf(We2[idx]);
    if (idx < 8192) { wca[idx] = f2bf(Wca[idx]); wcv[idx] = f2bf(Wcv[idx]); }
    if (idx < 256) {                    // wcomb[j] = sum_q Wr2[q]*Wr1[q][j]
        float s = 0.0f;
        for (int q = 0; q < 128; ++q) s += Wr2[q] * Wr1[q * 256 + idx];
        wcomb[idx] = s;
    }
    if (idx == 0) {                     // bc = br1 . Wr2 + br2
        float s = br2[0];
        for (int q = 0; q < 128; ++q) s += br1[q] * Wr2[q];
        bcp[0] = s;
    }
}

// ---------------- encoder: aud/vis = f @ We^T + be  (2-pass hi/lo A) --------
__global__ __launch_bounds__(256) void k_encoder(
    const float* __restrict__ f1, const float* __restrict__ f2,
    const float* __restrict__ be1, const float* __restrict__ be2,
    char* __restrict__ ws)
{
    const int w  = threadIdx.x >> 6;
    const int l  = threadIdx.x & 63;
    const int lr = l & 15, lg = l >> 4;
    const int mod = blockIdx.y;
    const float* f   = mod ? f2 : f1;
    const short* whi = (const short*)(ws + (mod ? OFF_WE2HI : OFF_WE1HI));
    const float* be  = mod ? be2 : be1;
    float* outp = (float*)(ws + (mod ? OFF_VIS : OFF_AUD));
    const long row = (long)blockIdx.x * 64 + w * 16 + lr;   // A-operand row

    f32x4 acc[8];
    #pragma unroll
    for (int nt = 0; nt < 8; ++nt) acc[nt] = (f32x4){0.f,0.f,0.f,0.f};

    for (int ks = 0; ks < 16; ++ks) {
        const int k0 = ks * 32 + lg * 8;
        const float* ap = f + row * 512 + k0;
        f4v a0 = *(const f4v*)ap;
        f4v a1 = *(const f4v*)(ap + 4);
        float av[8] = {a0[0],a0[1],a0[2],a0[3],a1[0],a1[1],a1[2],a1[3]};
        bhalf8 ahi, alo;
        #pragma unroll
        for (int i = 0; i < 8; ++i) {
            short h = f2bf(av[i]);
            ahi[i] = h;
            alo[i] = f2bf(av[i] - bf2f(h));
        }
        #pragma unroll
        for (int nt = 0; nt < 8; ++nt) {
            const int wrow = nt * 16 + lr;
            bhalf8 bhi = *(const bhalf8*)(whi + wrow * 512 + k0);
            acc[nt] = MFMA(ahi, bhi, acc[nt]);
            acc[nt] = MFMA(alo, bhi, acc[nt]);
        }
    }
    const long orow = (long)blockIdx.x * 64 + w * 16 + lg * 4;
    #pragma unroll
    for (int nt = 0; nt < 8; ++nt) {
        const int col = nt * 16 + lr;
        const float bias = be[col];
        #pragma unroll
        for (int r = 0; r < 4; ++r)
            outp[(orow + r) * 128 + col] = acc[nt][r] + bias;
    }
}

// ---------------- fused middle + collapsed regressor: one block per batch ----
__global__ __launch_bounds__(256) void k_fused(
    const float* __restrict__ waffa, const float* __restrict__ waffv,
    const float* __restrict__ Wa,   const float* __restrict__ Wv,
    const float* __restrict__ Wha,  const float* __restrict__ Whv,
    const char* __restrict__ ws, float* __restrict__ out)
{
    __shared__ __align__(16) short s_At[2][128][8];      // av bf16, [i][t] layout
    __shared__ __align__(16) short s_G[2][256][8];       // folded G bf16
    __shared__ __align__(16) char  s_zH[16384];          // z + H per-wave overlay
    __shared__ float s_waff[2][8][8];
    __shared__ float s_red[4][8];

    const int tid = threadIdx.x;
    const int b = blockIdx.x;
    const int w = tid >> 6, l = tid & 63, lr = l & 15, lg = l >> 4;
    const bool k8 = (lg == 0);          // lanes carrying the real K=8 slice

    const short* wcag  = (const short*)(ws + OFF_WCA);
    const short* wcvg  = (const short*)(ws + OFF_WCV);
    const float* wcomb = (const float*)(ws + OFF_WCOMB);
    const float* audp = (const float*)(ws + OFF_AUD) + (long)b * 1024;
    const float* visp = (const float*)(ws + OFF_VIS) + (long)b * 1024;

    // phase 0: stage av (bf16, transposed [i][t])
    #pragma unroll
    for (int i = 0; i < 4; ++i) {
        int idx = tid + 256 * i;          // 0..1023  ([t][i] source layout)
        int tt = idx >> 7, ii = idx & 127;
        s_At[0][ii][tt] = f2bf(audp[idx]);
        s_At[1][ii][tt] = f2bf(visp[idx]);
    }
    if (tid < 128) {
        const float* src = (tid < 64) ? waffa : waffv;
        s_waff[tid >> 6][(tid >> 3) & 7][tid & 7] = src[tid & 63];
    }
    __syncthreads();

    // phase 1: G' = (Waff @ av) * (scale*2*log2e)   [tanh prefold]
    const float kfold = (1.0f / 16.0f) * 2.0f * 1.44269504088896340736f;
    #pragma unroll
    for (int u = 0; u < 2; ++u) {
        int idx = tid + 256 * u;           // 0..511
        int m = idx >> 8, j = idx & 255;
        const short* avp = (j < 128) ? &s_At[0][j][0] : &s_At[1][j - 128][0];
        bhalf8 avv = *(const bhalf8*)avp;
        float avf[8];
        #pragma unroll
        for (int t = 0; t < 8; ++t) avf[t] = bf2f(avv[t]);
        float g[8] = {0,0,0,0,0,0,0,0};
        #pragma unroll
        for (int t = 0; t < 8; ++t)
            #pragma unroll
            for (int p = 0; p < 8; ++p) g[p] += s_waff[m][p][t] * avf[t];
        bhalf8 gv;
        #pragma unroll
        for (int p = 0; p < 8; ++p) gv[p] = f2bf(g[p] * kfold);
        *(bhalf8*)&s_G[m][j][0] = gv;
    }
    __syncthreads();

    const bhalf8 zf8 = {0,0,0,0,0,0,0,0};
    const f32x4  zf4 = {0.f,0.f,0.f,0.f};

    // preload collapsed-regressor weight frags
    f4v wcf[2][2];
    #pragma unroll
    for (int mod = 0; mod < 2; ++mod)
        #pragma unroll
        for (int mt = 0; mt < 2; ++mt)
            wcf[mod][mt] = *(const f4v*)(wcomb + mod*128 + (2*w+mt)*16 + lg*4);

    float pacc = 0.0f;   // per-thread partial of out[t=lr] (valid lr<8)

    // phase 2: per modality — M=tanh(At@G'), H=relu(M@Wca^T + At@Wa^T),
    //          pacc += (H@Wha^T + av) . wcomb
    for (int mod = 0; mod < 2; ++mod) {
        const short* wca = mod ? wcvg : wcag;
        const float* wha = mod ? Whv : Wha;
        const float* wa  = mod ? Wv  : Wa;

        bhalf8 atf[2];
        #pragma unroll
        for (int mt = 0; mt < 2; ++mt)
            atf[mt] = k8 ? *(const bhalf8*)&s_At[mod][(2*w+mt)*16 + lr][0] : zf8;

        f32x4 hacc[2][2];
        #pragma unroll
        for (int nt = 0; nt < 2; ++nt) {        // H init: At @ Wa^T  (K=8)
            bhalf8 wf = zf8;
            if (k8) {
                const float* p = wa + (nt*16 + lr) * 8;
                #pragma unroll
                for (int i = 0; i < 8; ++i) wf[i] = f2bf(p[i]);
            }
            #pragma unroll
            for (int mt = 0; mt < 2; ++mt) hacc[mt][nt] = MFMA(atf[mt], wf, zf4);
        }

        for (int cc = 0; cc < 4; ++cc) {        // 4 chunks of 64 cols
            f32x4 macc[2][4];
            #pragma unroll
            for (int nt = 0; nt < 4; ++nt) {
                bhalf8 gf = k8 ? *(const bhalf8*)&s_G[mod][cc*64 + nt*16 + lr][0] : zf8;
                #pragma unroll
                for (int mt = 0; mt < 2; ++mt) macc[mt][nt] = MFMA(atf[mt], gf, zf4);
            }
            WFENCE();   // prior z/H reads complete before overwrite
            #pragma unroll
            for (int mt = 0; mt < 2; ++mt)
            #pragma unroll
            for (int nt = 0; nt < 4; ++nt)
            #pragma unroll
            for (int r = 0; r < 4; ++r) {
                int zr = (2*w+mt)*16 + lg*4 + r;
                int zc = nt*16 + lr;
                float e  = fexp2(macc[mt][nt][r]);            // exp2 prefolded
                float zv = fmaf(-2.0f, frcp(e + 1.0f), 1.0f); // tanh
                int off = (zr * 128 + zc * 2) ^ ((zr & 7) << 4);
                *(short*)(s_zH + off) = f2bf(zv);
            }
            WFENCE();   // writes visible before reads
            #pragma unroll
            for (int ks = 0; ks < 2; ++ks) {
                bhalf8 az[2];
                #pragma unroll
                for (int mt = 0; mt < 2; ++mt) {
                    int mrow = (2*w+mt)*16 + lr;
                    int off = (mrow * 128 + (ks*32 + lg*8) * 2) ^ ((mrow & 7) << 4);
                    az[mt] = *(const bhalf8*)(s_zH + off);
                }
                #pragma unroll
                for (int nt = 0; nt < 2; ++nt) {
                    bhalf8 bw = *(const bhalf8*)(wca + (nt*16 + lr)*256 + cc*64 + ks*32 + lg*8);
                    #pragma unroll
                    for (int mt = 0; mt < 2; ++mt)
                        hacc[mt][nt] = MFMA(az[mt], bw, hacc[mt][nt]);
                }
            }
        }
        WFENCE();       // last z reads done before H overlay writes (same bytes)
        #pragma unroll
        for (int mt = 0; mt < 2; ++mt)          // relu -> H (per-wave region)
        #pragma unroll
        for (int nt = 0; nt < 2; ++nt)
        #pragma unroll
        for (int r = 0; r < 4; ++r) {
            int rr = mt*16 + lg*4 + r;
            int off = w*4096 + rr*80 + (nt*16 + lr)*2;
            *(short*)(s_zH + off) = f2bf(fmaxf(hacc[mt][nt][r], 0.0f));
        }
        WFENCE();
        bhalf8 whaf = zf8;                       // Wha^T B-frag (N pad to 16)
        if (lr < 8) {
            const float* p = wha + lr*32 + lg*8;
            #pragma unroll
            for (int i = 0; i < 8; ++i) whaf[i] = f2bf(p[i]);
        }
        #pragma unroll
        for (int mt = 0; mt < 2; ++mt) {
            int rr = mt*16 + lr;
            bhalf8 af = *(const bhalf8*)(s_zH + w*4096 + rr*80 + lg*16);
            f32x4 oa = MFMA(af, whaf, zf4);
            if (lr < 8) {
                #pragma unroll
                for (int r = 0; r < 4; ++r) {
                    int irow = (2*w+mt)*16 + lg*4 + r;
                    float val = oa[r] + bf2f(s_At[mod][irow][lr]);  // + residual
                    pacc += val * wcf[mod][mt][r];
                }
            }
        }
        WFENCE();       // H reads done before next modality's z writes
    }

    // reduce pacc over lg (lanes lr, lr+16, lr+32, lr+48) then over waves
    pacc += __shfl_xor(pacc, 16, 64);
    pacc += __shfl_xor(pacc, 32, 64);
    if (l < 8) s_red[w][l] = pacc;
    __syncthreads();
    if (tid < 8) {
        float s = *(const float*)(ws + OFF_BC);
        #pragma unroll
        for (int q = 0; q < 4; ++q) s += s_red[q][tid];
        out[b*8 + tid] = s;
    }
}

extern "C" void kernel_launch(void* const* d_in, const int* in_sizes, int n_in,
                              void* d_out, int out_size, void* d_ws, size_t ws_size,
                              hipStream_t stream)
{
    const float* f1    = (const float*)d_in[0];
    const float* f2    = (const float*)d_in[1];
    const float* We1   = (const float*)d_in[2];
    const float* be1   = (const float*)d_in[3];
    const float* We2   = (const float*)d_in[4];
    const float* be2   = (const float*)d_in[5];
    const float* Waffa = (const float*)d_in[6];
    const float* Waffv = (const float*)d_in[7];
    const float* Wa    = (const float*)d_in[8];
    const float* Wv    = (const float*)d_in[9];
    const float* Wca   = (const float*)d_in[10];
    const float* Wcv   = (const float*)d_in[11];
    const float* Wha   = (const float*)d_in[12];
    const float* Whv   = (const float*)d_in[13];
    const float* Wr1   = (const float*)d_in[14];
    const float* br1   = (const float*)d_in[15];
    const float* Wr2   = (const float*)d_in[16];
    const float* br2   = (const float*)d_in[17];
    char* ws = (char*)d_ws;
    float* out = (float*)d_out;

    k_prep   <<<256, 256, 0, stream>>>(We1, We2, Wca, Wcv, Wr1, br1, Wr2, br2, ws);
    k_encoder<<<dim3(512, 2), 256, 0, stream>>>(f1, f2, be1, be2, ws);
    k_fused  <<<4096, 256, 0, stream>>>(Waffa, Waffv, Wa, Wv, Wha, Whv, ws, out);
}